// Round 3
// baseline (237.485 us; speedup 1.0000x reference)
//
#include <hip/hip_runtime.h>

#define B_ 2048
#define N_ 1024
#define M_ 4
#define T_ 64
#define R_ 128
#define C_ 10

typedef _Float16 half8 __attribute__((ext_vector_type(8)));
typedef _Float16 half2v __attribute__((ext_vector_type(2)));
typedef float float4v __attribute__((ext_vector_type(4)));
typedef unsigned short ushort_t;
typedef unsigned int uint_t;

__device__ __forceinline__ uint_t dup16(_Float16 h) {
    union { _Float16 h; ushort_t s; } v; v.h = h;
    return (uint_t)v.s | ((uint_t)v.s << 16);
}
__device__ __forceinline__ uint_t pk16(float a, float b) {
    union { _Float16 h; ushort_t s; } x, y;
    x.h = (_Float16)a; y.h = (_Float16)b;
    return (uint_t)x.s | ((uint_t)y.s << 16);
}

// Kernel 1: feature map + per-division average. Inputs FLOAT32.
// div16[t*B + b] = {pk(phi0,phi1), pk(phi2,phi3)} as f16 pairs.
__global__ void k_div(const float* __restrict__ tensor, uint2* __restrict__ div16) {
    int gid = blockIdx.x * 256 + threadIdx.x;    // 0 .. B*T-1
    int t = gid >> 11;                           // /2048
    int b = gid & 2047;
    const float4* tp = (const float4*)(tensor + b * N_ + t * 16);
    float a0 = 0.f, a1 = 0.f, a2 = 0.f, a3 = 0.f;
#pragma unroll
    for (int v = 0; v < 4; ++v) {
        float4 xv = tp[v];
        float xs[4] = {xv.x, xv.y, xv.z, xv.w};
#pragma unroll
        for (int p = 0; p < 4; ++p) {
            float ang = 1.57079632679f * xs[p];
            float s, c;
            __sincosf(ang, &s, &c);
            float c2 = c * c, s2 = s * s;
            a0 += c2 * c; a1 += c2 * s; a2 += c * s2; a3 += s2 * s;
        }
    }
    const float sc = 1.0f / 16.0f;
    a0 *= sc; a1 *= sc; a2 *= sc; a3 *= sc;
    uint2 o; o.x = pk16(a0, a1); o.y = pk16(a2, a3);
    div16[gid] = o;
}

// Kernel 2: reorder w_mid (FLOAT32) into MFMA B-fragment-linear f16.
// Wt index = ((c*8 + nt)*16 + ks)*64 + lane, 8 f16 per entry (one uint4).
// B-fragment: lane holds B[k = (lane>>4)*8 + j + 32*ks][col = nt*16 + (lane&15)],
// where k = i*4 + m (m inner) and W[k][o] = w_mid[c,i,m,o].
__global__ void k_wt(const float* __restrict__ w_mid, uint4* __restrict__ wt) {
    int gid = blockIdx.x * 256 + threadIdx.x;    // 0 .. 81919
    int c  = gid >> 13;
    int nt = (gid >> 10) & 7;
    int ks = (gid >> 6) & 15;
    int l  = gid & 63;
    int q = l >> 4;
    int col = nt * 16 + (l & 15);
    ushort_t h[8];
#pragma unroll
    for (int j = 0; j < 8; ++j) {
        int kl = q * 8 + j;                      // k within 32-wide window
        int i  = ks * 8 + (kl >> 2);
        int m  = kl & 3;
        float v = w_mid[((c * R_ + i) * M_ + m) * R_ + col];
        union { _Float16 hh; ushort_t s; } u; u.hh = (_Float16)v; h[j] = u.s;
    }
    uint4 o;
    o.x = (uint_t)h[0] | ((uint_t)h[1] << 16);
    o.y = (uint_t)h[2] | ((uint_t)h[3] << 16);
    o.z = (uint_t)h[4] | ((uint_t)h[5] << 16);
    o.w = (uint_t)h[6] | ((uint_t)h[7] << 16);
    wt[gid] = o;
}

// Kernel 3: the 64-step recurrence. Block = (b-tile of 32, category c), 4 waves.
// Wave w owns output cols [32w, 32w+32) (2 n-tiles). W B-frags live in registers.
// State in LDS ping-pong, stored as duplicated f16 dwords, XOR-swizzled.
__global__ void __launch_bounds__(256, 2)
k_main(const uint2* __restrict__ div16, const uint4* __restrict__ wt,
       const float* __restrict__ w_first, const float* __restrict__ w_last,
       float* __restrict__ logits) {
    __shared__ uint_t st[8192];      // 2 buffers x 32 rows x 128 dwords
    __shared__ float uf[128];
    __shared__ float red[256];

    const int tid = threadIdx.x;
    const int c  = blockIdx.y;
    const int b0 = blockIdx.x * 32;
    const int lane = tid & 63;
    const int w = tid >> 6;
    const int q = lane >> 4;
    const int r15 = lane & 15;
    const int swz = r15 << 1;

    // Load W fragments (held in VGPRs for the whole kernel).
    half8 wf[2][16];
#pragma unroll
    for (int nt = 0; nt < 2; ++nt) {
        int ntg = w * 2 + nt;
#pragma unroll
        for (int ks = 0; ks < 16; ++ks) {
            union { uint4 u; half8 h; } cv;
            cv.u = wt[(c * 8 + ntg) * 1024 + ks * 64 + lane];
            wf[nt][ks] = cv.h;
        }
    }

    // Initial state: state0[i] = sum_m w_first[c,0,m,i]  (same for every row).
    if (tid < 128) {
        float s = 0.f;
#pragma unroll
        for (int m = 0; m < 4; ++m) s += w_first[(c * 4 + m) * 128 + tid];
        uint_t d = dup16((_Float16)s);
#pragma unroll
        for (int row = 0; row < 32; ++row)
            st[row * 128 + (tid ^ ((row & 15) << 1))] = d;
    }
    __syncthreads();

#pragma unroll 2
    for (int t = 0; t < T_; ++t) {
        const int rb = (t & 1) ? 4096 : 0;
        const int wb = 4096 - rb;

        // x_t for the rows this lane feeds as A-operand (row = r15 + 16*rt).
        uint2 xv0 = div16[t * B_ + b0 + r15];
        uint2 xv1 = div16[t * B_ + b0 + 16 + r15];
        half2v x01_0 = __builtin_bit_cast(half2v, xv0.x);
        half2v x23_0 = __builtin_bit_cast(half2v, xv0.y);
        half2v x01_1 = __builtin_bit_cast(half2v, xv1.x);
        half2v x23_1 = __builtin_bit_cast(half2v, xv1.y);

        float4v acc[2][2];
#pragma unroll
        for (int a = 0; a < 2; ++a)
#pragma unroll
            for (int b = 0; b < 2; ++b) acc[a][b] = (float4v){0.f, 0.f, 0.f, 0.f};

#pragma unroll
        for (int ks = 0; ks < 16; ++ks) {
            int off = rb + r15 * 128 + ((q * 2 + ks * 8) ^ swz);
            uint2 sv0 = *(const uint2*)&st[off];          // rt = 0
            uint2 sv1 = *(const uint2*)&st[off + 2048];   // rt = 1 (+16 rows)

            {
                half2v s0 = __builtin_bit_cast(half2v, sv0.x);
                half2v s1 = __builtin_bit_cast(half2v, sv0.y);
                half2v a0 = s0 * x01_0, a1 = s0 * x23_0;
                half2v a2 = s1 * x01_0, a3 = s1 * x23_0;
                half8 af = {a0.x, a0.y, a1.x, a1.y, a2.x, a2.y, a3.x, a3.y};
                acc[0][0] = __builtin_amdgcn_mfma_f32_16x16x32_f16(af, wf[0][ks], acc[0][0], 0, 0, 0);
                acc[0][1] = __builtin_amdgcn_mfma_f32_16x16x32_f16(af, wf[1][ks], acc[0][1], 0, 0, 0);
            }
            {
                half2v s0 = __builtin_bit_cast(half2v, sv1.x);
                half2v s1 = __builtin_bit_cast(half2v, sv1.y);
                half2v a0 = s0 * x01_1, a1 = s0 * x23_1;
                half2v a2 = s1 * x01_1, a3 = s1 * x23_1;
                half8 af = {a0.x, a0.y, a1.x, a1.y, a2.x, a2.y, a3.x, a3.y};
                acc[1][0] = __builtin_amdgcn_mfma_f32_16x16x32_f16(af, wf[0][ks], acc[1][0], 0, 0, 0);
                acc[1][1] = __builtin_amdgcn_mfma_f32_16x16x32_f16(af, wf[1][ks], acc[1][1], 0, 0, 0);
            }
        }

        // Write new state (C/D layout: col = lane&15, row = (lane>>4)*4 + reg).
#pragma unroll
        for (int rt = 0; rt < 2; ++rt) {
#pragma unroll
            for (int nt = 0; nt < 2; ++nt) {
                int colg = w * 32 + nt * 16 + r15;
#pragma unroll
                for (int rg = 0; rg < 4; ++rg) {
                    int row = rt * 16 + q * 4 + rg;
                    uint_t d = dup16((_Float16)acc[rt][nt][rg]);
                    st[wb + row * 128 + (colg ^ ((row & 15) << 1))] = d;
                }
            }
        }
        __syncthreads();
    }

    // Final contraction: logits[b,c] = sum_i state[b,i] * sum_m w_last[c,i,m].
    if (tid < 128) {
        float s = 0.f;
#pragma unroll
        for (int m = 0; m < 4; ++m) s += w_last[(c * 128 + tid) * 4 + m];
        uf[tid] = s;
    }
    __syncthreads();
    {
        int row = tid & 31, seg = tid >> 5;
        float p = 0.f;
#pragma unroll
        for (int k2 = 0; k2 < 16; ++k2) {
            int i = seg * 16 + k2;
            uint_t d = st[row * 128 + (i ^ ((row & 15) << 1))];  // final state in buf0
            half2v hh = __builtin_bit_cast(half2v, d);
            p += (float)hh.x * uf[i];
        }
        red[seg * 32 + row] = p;
    }
    __syncthreads();
    if (tid < 32) {
        float s = 0.f;
#pragma unroll
        for (int sg = 0; sg < 8; ++sg) s += red[sg * 32 + tid];
        logits[(b0 + tid) * C_ + c] = s;
    }
}

// Kernel 4: log-softmax over C=10, output FLOAT32.
__global__ void k_lsm(const float* __restrict__ logits, float* __restrict__ out) {
    int b = blockIdx.x * 256 + threadIdx.x;
    float x[C_];
    float mx = -1e30f;
#pragma unroll
    for (int c = 0; c < C_; ++c) { x[c] = logits[b * C_ + c]; mx = fmaxf(mx, x[c]); }
    float s = 0.f;
#pragma unroll
    for (int c = 0; c < C_; ++c) s += __expf(x[c] - mx);
    float lse = mx + __logf(s);
#pragma unroll
    for (int c = 0; c < C_; ++c) out[b * C_ + c] = x[c] - lse;
}

extern "C" void kernel_launch(void* const* d_in, const int* in_sizes, int n_in,
                              void* d_out, int out_size, void* d_ws, size_t ws_size,
                              hipStream_t stream) {
    const float* tensor  = (const float*)d_in[0];   // (B,N)      f32
    const float* w_first = (const float*)d_in[1];   // (C,1,M,R)  f32
    const float* w_mid   = (const float*)d_in[2];   // (C,R,M,R)  f32
    const float* w_last  = (const float*)d_in[3];   // (C,R,M,1)  f32
    char* ws = (char*)d_ws;
    uint2* div16 = (uint2*)ws;                               // 131072 * 8 B = 1 MiB
    uint4* wt    = (uint4*)(ws + 1048576);                   //  81920 * 16 B
    float* logits = (float*)(ws + 1048576 + 1310720);        //  20480 * 4 B
    float* out = (float*)d_out;                              // (B,C) f32

    k_div<<<512, 256, 0, stream>>>(tensor, div16);
    k_wt<<<320, 256, 0, stream>>>(w_mid, wt);
    k_main<<<dim3(64, 10), 256, 0, stream>>>(div16, wt, w_first, w_last, logits);
    k_lsm<<<8, 256, 0, stream>>>(logits, out);
}

// Round 5
// 228.076 us; speedup vs baseline: 1.0413x; 1.0413x over previous
//
#include <hip/hip_runtime.h>

#define B_ 2048
#define N_ 1024
#define M_ 4
#define T_ 64
#define R_ 128
#define C_ 10

typedef _Float16 half8 __attribute__((ext_vector_type(8)));
typedef _Float16 half2v __attribute__((ext_vector_type(2)));
typedef __fp16 fp16x2 __attribute__((ext_vector_type(2)));
typedef float float4v __attribute__((ext_vector_type(4)));
typedef unsigned short ushort_t;
typedef unsigned int uint_t;

__device__ __forceinline__ uint_t duppk(float a) {
    fp16x2 h = __builtin_amdgcn_cvt_pkrtz(a, a);   // one v_cvt_pkrtz_f16_f32
    return __builtin_bit_cast(uint_t, h);
}
__device__ __forceinline__ uint_t dup16(_Float16 h) {
    union { _Float16 h; ushort_t s; } v; v.h = h;
    return (uint_t)v.s | ((uint_t)v.s << 16);
}
__device__ __forceinline__ uint_t pk16(float a, float b) {
    fp16x2 h = __builtin_amdgcn_cvt_pkrtz(a, b);
    return __builtin_bit_cast(uint_t, h);
}

// Fused preprocessing: blocks [0,512) do the feature-map+average (k_div role),
// blocks [512,832) reorder w_mid into MFMA B-fragment-linear f16 (k_wt role).
__global__ void k_pre(const float* __restrict__ tensor, const float* __restrict__ w_mid,
                      uint2* __restrict__ div16, uint4* __restrict__ wt) {
    if (blockIdx.x < 512) {
        int gid = blockIdx.x * 256 + threadIdx.x;    // 0 .. B*T-1
        int t = gid >> 11;                           // /2048
        int b = gid & 2047;
        const float4* tp = (const float4*)(tensor + b * N_ + t * 16);
        float a0 = 0.f, a1 = 0.f, a2 = 0.f, a3 = 0.f;
#pragma unroll
        for (int v = 0; v < 4; ++v) {
            float4 xv = tp[v];
            float xs[4] = {xv.x, xv.y, xv.z, xv.w};
#pragma unroll
            for (int p = 0; p < 4; ++p) {
                float ang = 1.57079632679f * xs[p];
                float s, c;
                __sincosf(ang, &s, &c);
                float c2 = c * c, s2 = s * s;
                a0 += c2 * c; a1 += c2 * s; a2 += c * s2; a3 += s2 * s;
            }
        }
        const float sc = 1.0f / 16.0f;
        uint2 o; o.x = pk16(a0 * sc, a1 * sc); o.y = pk16(a2 * sc, a3 * sc);
        div16[gid] = o;
    } else {
        int gid = (blockIdx.x - 512) * 256 + threadIdx.x;   // 0 .. 81919
        int c  = gid >> 13;
        int nt = (gid >> 10) & 7;
        int ks = (gid >> 6) & 15;
        int l  = gid & 63;
        int q = l >> 4;
        int col = nt * 16 + (l & 15);
        ushort_t h[8];
#pragma unroll
        for (int j = 0; j < 8; ++j) {
            int kl = q * 8 + j;                      // k within 32-wide window
            int i  = ks * 8 + (kl >> 2);
            int m  = kl & 3;
            float v = w_mid[((c * R_ + i) * M_ + m) * R_ + col];
            union { _Float16 hh; ushort_t s; } u; u.hh = (_Float16)v; h[j] = u.s;
        }
        uint4 o;
        o.x = (uint_t)h[0] | ((uint_t)h[1] << 16);
        o.y = (uint_t)h[2] | ((uint_t)h[3] << 16);
        o.z = (uint_t)h[4] | ((uint_t)h[5] << 16);
        o.w = (uint_t)h[6] | ((uint_t)h[7] << 16);
        wt[gid] = o;
    }
}

// The 64-step recurrence. Block = (b-tile of 32, category c), 4 waves.
// Wave w owns output cols [32w, 32w+32) (2 n-tiles). W B-frags live in registers.
// State in LDS ping-pong (duplicated-f16 dwords, XOR-swizzled). All x for the
// block's 32 rows staged into LDS up front -> no global traffic in the t-loop.
__global__ void __launch_bounds__(256, 2)
k_main(const uint2* __restrict__ div16, const uint4* __restrict__ wt,
       const float* __restrict__ w_first, const float* __restrict__ w_last,
       float* __restrict__ logits) {
    __shared__ uint_t st[8192];      // 2 buffers x 32 rows x 128 dwords (32 KB)
    __shared__ uint2 xbuf[2048];     // 64 t x 32 rows (16 KB)
    __shared__ float uf[128];
    __shared__ float red[256];

    const int tid = threadIdx.x;
    const int c  = blockIdx.y;
    const int b0 = blockIdx.x * 32;
    const int lane = tid & 63;
    const int w = tid >> 6;
    const int q = lane >> 4;
    const int r15 = lane & 15;
    const int swz = r15 << 1;

    // Stage x: xbuf[t*32 + r] = div16[t*B + b0 + r]; coalesced 256B segments.
#pragma unroll
    for (int k = 0; k < 8; ++k) {
        int idx = k * 256 + tid;               // == t*32 + r
        int t = idx >> 5, r = idx & 31;
        xbuf[idx] = div16[t * B_ + b0 + r];
    }

    // Load W fragments (held in registers for the whole kernel).
    half8 wf[2][16];
#pragma unroll
    for (int nt = 0; nt < 2; ++nt) {
        int ntg = w * 2 + nt;
#pragma unroll
        for (int ks = 0; ks < 16; ++ks) {
            union { uint4 u; half8 h; } cv;
            cv.u = wt[(c * 8 + ntg) * 1024 + ks * 64 + lane];
            wf[nt][ks] = cv.h;
        }
    }

    // Initial state: state0[i] = sum_m w_first[c,0,m,i]  (same for every row).
    if (tid < 128) {
        float s = 0.f;
#pragma unroll
        for (int m = 0; m < 4; ++m) s += w_first[(c * 4 + m) * 128 + tid];
        uint_t d = dup16((_Float16)s);
#pragma unroll
        for (int row = 0; row < 32; ++row)
            st[row * 128 + (tid ^ ((row & 15) << 1))] = d;
    }
    __syncthreads();

#pragma unroll 2
    for (int t = 0; t < T_; ++t) {
        const int rb = (t & 1) ? 4096 : 0;
        const int wb = 4096 - rb;

        // x_t for the rows this lane feeds as A-operand (row = r15 + 16*rt).
        uint2 xv0 = xbuf[t * 32 + r15];
        uint2 xv1 = xbuf[t * 32 + 16 + r15];
        half2v x01_0 = __builtin_bit_cast(half2v, xv0.x);
        half2v x23_0 = __builtin_bit_cast(half2v, xv0.y);
        half2v x01_1 = __builtin_bit_cast(half2v, xv1.x);
        half2v x23_1 = __builtin_bit_cast(half2v, xv1.y);

        float4v acc[2][2];
#pragma unroll
        for (int a = 0; a < 2; ++a)
#pragma unroll
            for (int b = 0; b < 2; ++b) acc[a][b] = (float4v){0.f, 0.f, 0.f, 0.f};

#pragma unroll
        for (int ks = 0; ks < 16; ++ks) {
            int off = rb + r15 * 128 + ((q * 2 + ks * 8) ^ swz);
            uint2 sv0 = *(const uint2*)&st[off];          // rt = 0
            uint2 sv1 = *(const uint2*)&st[off + 2048];   // rt = 1 (+16 rows)

            {
                half2v s0 = __builtin_bit_cast(half2v, sv0.x);
                half2v s1 = __builtin_bit_cast(half2v, sv0.y);
                half2v a0 = s0 * x01_0, a1 = s0 * x23_0;
                half2v a2 = s1 * x01_0, a3 = s1 * x23_0;
                half8 af = {a0.x, a0.y, a1.x, a1.y, a2.x, a2.y, a3.x, a3.y};
                acc[0][0] = __builtin_amdgcn_mfma_f32_16x16x32_f16(af, wf[0][ks], acc[0][0], 0, 0, 0);
                acc[0][1] = __builtin_amdgcn_mfma_f32_16x16x32_f16(af, wf[1][ks], acc[0][1], 0, 0, 0);
            }
            {
                half2v s0 = __builtin_bit_cast(half2v, sv1.x);
                half2v s1 = __builtin_bit_cast(half2v, sv1.y);
                half2v a0 = s0 * x01_1, a1 = s0 * x23_1;
                half2v a2 = s1 * x01_1, a3 = s1 * x23_1;
                half8 af = {a0.x, a0.y, a1.x, a1.y, a2.x, a2.y, a3.x, a3.y};
                acc[1][0] = __builtin_amdgcn_mfma_f32_16x16x32_f16(af, wf[0][ks], acc[1][0], 0, 0, 0);
                acc[1][1] = __builtin_amdgcn_mfma_f32_16x16x32_f16(af, wf[1][ks], acc[1][1], 0, 0, 0);
            }
        }

        // Write new state (C/D layout: col = lane&15, row = (lane>>4)*4 + reg).
#pragma unroll
        for (int rt = 0; rt < 2; ++rt) {
#pragma unroll
            for (int nt = 0; nt < 2; ++nt) {
                int colg = w * 32 + nt * 16 + r15;
#pragma unroll
                for (int rg = 0; rg < 4; ++rg) {
                    int row = rt * 16 + q * 4 + rg;
                    uint_t d = duppk(acc[rt][nt][rg]);
                    st[wb + row * 128 + (colg ^ ((row & 15) << 1))] = d;
                }
            }
        }
        __syncthreads();
    }

    // Final contraction: logits[b,c] = sum_i state[b,i] * sum_m w_last[c,i,m].
    if (tid < 128) {
        float s = 0.f;
#pragma unroll
        for (int m = 0; m < 4; ++m) s += w_last[(c * 128 + tid) * 4 + m];
        uf[tid] = s;
    }
    __syncthreads();
    {
        int row = tid & 31, seg = tid >> 5;
        float p = 0.f;
#pragma unroll
        for (int k2 = 0; k2 < 16; ++k2) {
            int i = seg * 16 + k2;
            uint_t d = st[row * 128 + (i ^ ((row & 15) << 1))];  // final state in buf0
            half2v hh = __builtin_bit_cast(half2v, d);
            p += (float)hh.x * uf[i];
        }
        red[seg * 32 + row] = p;
    }
    __syncthreads();
    if (tid < 32) {
        float s = 0.f;
#pragma unroll
        for (int sg = 0; sg < 8; ++sg) s += red[sg * 32 + tid];
        logits[(b0 + tid) * C_ + c] = s;
    }
}

// Log-softmax over C=10, output FLOAT32.
__global__ void k_lsm(const float* __restrict__ logits, float* __restrict__ out) {
    int b = blockIdx.x * 256 + threadIdx.x;
    float x[C_];
    float mx = -1e30f;
#pragma unroll
    for (int c = 0; c < C_; ++c) { x[c] = logits[b * C_ + c]; mx = fmaxf(mx, x[c]); }
    float s = 0.f;
#pragma unroll
    for (int c = 0; c < C_; ++c) s += __expf(x[c] - mx);
    float lse = mx + __logf(s);
#pragma unroll
    for (int c = 0; c < C_; ++c) out[b * C_ + c] = x[c] - lse;
}

extern "C" void kernel_launch(void* const* d_in, const int* in_sizes, int n_in,
                              void* d_out, int out_size, void* d_ws, size_t ws_size,
                              hipStream_t stream) {
    const float* tensor  = (const float*)d_in[0];   // (B,N)      f32
    const float* w_first = (const float*)d_in[1];   // (C,1,M,R)  f32
    const float* w_mid   = (const float*)d_in[2];   // (C,R,M,R)  f32
    const float* w_last  = (const float*)d_in[3];   // (C,R,M,1)  f32
    char* ws = (char*)d_ws;
    uint2* div16 = (uint2*)ws;                               // 131072 * 8 B = 1 MiB
    uint4* wt    = (uint4*)(ws + 1048576);                   //  81920 * 16 B
    float* logits = (float*)(ws + 1048576 + 1310720);        //  20480 * 4 B
    float* out = (float*)d_out;                              // (B,C) f32

    k_pre<<<832, 256, 0, stream>>>(tensor, w_mid, div16, wt);
    k_main<<<dim3(64, 10), 256, 0, stream>>>(div16, wt, w_first, w_last, logits);
    k_lsm<<<8, 256, 0, stream>>>(logits, out);
}

// Round 6
// 220.167 us; speedup vs baseline: 1.0787x; 1.0359x over previous
//
#include <hip/hip_runtime.h>

#define B_ 2048
#define N_ 1024
#define M_ 4
#define T_ 64
#define R_ 128
#define C_ 10

typedef _Float16 half8 __attribute__((ext_vector_type(8)));
typedef _Float16 half2v __attribute__((ext_vector_type(2)));
typedef __fp16 fp16x2 __attribute__((ext_vector_type(2)));
typedef float float4v __attribute__((ext_vector_type(4)));
typedef unsigned short ushort_t;
typedef unsigned int uint_t;

__device__ __forceinline__ uint_t pk16(float a, float b) {
    fp16x2 h = __builtin_amdgcn_cvt_pkrtz(a, b);
    return __builtin_bit_cast(uint_t, h);
}

// Preprocessing: blocks [0,512) feature-map+average -> div16 (f16 pairs);
// blocks [512,832) pack w_mid into MFMA *A-operand* fragments (role-swapped):
// frag(c,w,ot,m,ks)[lane] = 8 f16 of A[row=o][k=i], o = 32w+16ot+(lane&15),
// i = 32ks + 8*(lane>>4) + j.  W_m[o][i] = w_mid[c,i,m,o].
__global__ void k_pre(const float* __restrict__ tensor, const float* __restrict__ w_mid,
                      uint2* __restrict__ div16, uint4* __restrict__ wt) {
    if (blockIdx.x < 512) {
        int gid = blockIdx.x * 256 + threadIdx.x;    // 0 .. B*T-1
        int t = gid >> 11;
        int b = gid & 2047;
        const float4* tp = (const float4*)(tensor + b * N_ + t * 16);
        float a0 = 0.f, a1 = 0.f, a2 = 0.f, a3 = 0.f;
#pragma unroll
        for (int v = 0; v < 4; ++v) {
            float4 xv = tp[v];
            float xs[4] = {xv.x, xv.y, xv.z, xv.w};
#pragma unroll
            for (int p = 0; p < 4; ++p) {
                float ang = 1.57079632679f * xs[p];
                float s, c;
                __sincosf(ang, &s, &c);
                float c2 = c * c, s2 = s * s;
                a0 += c2 * c; a1 += c2 * s; a2 += c * s2; a3 += s2 * s;
            }
        }
        const float sc = 1.0f / 16.0f;
        uint2 o; o.x = pk16(a0 * sc, a1 * sc); o.y = pk16(a2 * sc, a3 * sc);
        div16[gid] = o;
    } else {
        int gid = (blockIdx.x - 512) * 256 + threadIdx.x;   // 0 .. 81919
        int lane = gid & 63;
        int ks = (gid >> 6) & 3;
        int m  = (gid >> 8) & 3;
        int ot = (gid >> 10) & 1;
        int w  = (gid >> 11) & 3;
        int c  = gid >> 13;
        int q = lane >> 4, r15 = lane & 15;
        int o = w * 32 + ot * 16 + r15;
        ushort_t h[8];
#pragma unroll
        for (int j = 0; j < 8; ++j) {
            int i = ks * 32 + q * 8 + j;
            float v = w_mid[((c * R_ + i) * M_ + m) * R_ + o];
            union { _Float16 hh; ushort_t s; } u; u.hh = (_Float16)v; h[j] = u.s;
        }
        uint4 ov;
        ov.x = (uint_t)h[0] | ((uint_t)h[1] << 16);
        ov.y = (uint_t)h[2] | ((uint_t)h[3] << 16);
        ov.z = (uint_t)h[4] | ((uint_t)h[5] << 16);
        ov.w = (uint_t)h[6] | ((uint_t)h[7] << 16);
        wt[gid] = ov;
    }
}

// 64-step recurrence, per-m decomposition, role-swapped MFMA.
// Block = (btile 32, c), 4 waves; wave w owns o in [32w, 32w+32).
// A = W (registers), B = state (LDS, plain f16, 16B-chunk XOR swizzle),
// D[o][b]; epilogue applies x (f32) per m and writes next state.
__global__ void __launch_bounds__(256, 2)
k_main(const uint2* __restrict__ div16, const uint4* __restrict__ wt,
       const float* __restrict__ w_first, const float* __restrict__ w_last,
       float* __restrict__ logits) {
    __shared__ __align__(16) char st[16384];     // 2 buffers x 32 b x 256 B
    __shared__ __align__(16) float xbuf[8192];   // [t][b][m] f32, 32 KB
    __shared__ float uf[128];
    __shared__ float red[256];

    const int tid = threadIdx.x;
    const int c  = blockIdx.y;
    const int b0 = blockIdx.x * 32;
    const int lane = tid & 63;
    const int w = tid >> 6;
    const int q = lane >> 4;
    const int r15 = lane & 15;

    // W fragments: 32 x uint4 = 128 VGPRs, resident for the whole kernel.
    half8 wf[2][4][4];   // [ot][m][ks]
    {
        const uint4* wb = wt + (c * 4 + w) * 2048 + lane;
#pragma unroll
        for (int ot = 0; ot < 2; ++ot)
#pragma unroll
            for (int m = 0; m < 4; ++m)
#pragma unroll
                for (int ks = 0; ks < 4; ++ks) {
                    union { uint4 u; half8 h; } cv;
                    cv.u = wb[(ot * 16 + m * 4 + ks) * 64];
                    wf[ot][m][ks] = cv.h;
                }
    }

    // Stage x as f32: xbuf[t*32+r] = cvt(div16[t*B + b0 + r])
#pragma unroll
    for (int k = 0; k < 8; ++k) {
        int idx = k * 256 + tid;               // t*32 + r
        int t = idx >> 5, r = idx & 31;
        uint2 d = div16[t * B_ + b0 + r];
        half2v lo = __builtin_bit_cast(half2v, d.x);
        half2v hi = __builtin_bit_cast(half2v, d.y);
        ((float4*)xbuf)[idx] = make_float4((float)lo.x, (float)lo.y, (float)hi.x, (float)hi.y);
    }

    // Initial state: state0[b][i] = sum_m w_first[c,0,m,i] (same for all b).
    if (tid < 128) {
        float s = 0.f;
#pragma unroll
        for (int m = 0; m < 4; ++m) s += w_first[(c * 4 + m) * 128 + tid];
        union { _Float16 hh; ushort_t u; } cv; cv.hh = (_Float16)s;
        int cb = tid >> 3, off = (tid & 7) * 2;
#pragma unroll
        for (int b = 0; b < 32; ++b)
            *(ushort_t*)(st + b * 256 + ((cb ^ (b & 15)) << 4) + off) = cv.u;
    }
    __syncthreads();

    for (int t = 0; t < T_; ++t) {
        const char* rbp = st + ((t & 1) ? 8192 : 0);
        char* wbp = st + ((t & 1) ? 0 : 8192);

        float4v acc[4][2][2];                  // [m][ot][bt]
        const float4v z4 = {0.f, 0.f, 0.f, 0.f};

#pragma unroll
        for (int ks = 0; ks < 4; ++ks) {
            int ch = ((ks * 4 + q) ^ r15) << 4;
            uint4 sr0 = *(const uint4*)(rbp + r15 * 256 + ch);
            uint4 sr1 = *(const uint4*)(rbp + (16 + r15) * 256 + ch);
            half8 Bf0 = __builtin_bit_cast(half8, sr0);
            half8 Bf1 = __builtin_bit_cast(half8, sr1);
#pragma unroll
            for (int m = 0; m < 4; ++m)
#pragma unroll
                for (int ot = 0; ot < 2; ++ot) {
                    if (ks == 0) {
                        acc[m][ot][0] = __builtin_amdgcn_mfma_f32_16x16x32_f16(wf[ot][m][0], Bf0, z4, 0, 0, 0);
                        acc[m][ot][1] = __builtin_amdgcn_mfma_f32_16x16x32_f16(wf[ot][m][0], Bf1, z4, 0, 0, 0);
                    } else {
                        acc[m][ot][0] = __builtin_amdgcn_mfma_f32_16x16x32_f16(wf[ot][m][ks], Bf0, acc[m][ot][0], 0, 0, 0);
                        acc[m][ot][1] = __builtin_amdgcn_mfma_f32_16x16x32_f16(wf[ot][m][ks], Bf1, acc[m][ot][1], 0, 0, 0);
                    }
                }
        }

        // Epilogue: next[b][o] = sum_m x[b][m]*acc_m ; D layout row=o(q*4+rg), col=b(r15).
        float4 x0 = ((const float4*)xbuf)[t * 32 + r15];
        float4 x1 = ((const float4*)xbuf)[t * 32 + 16 + r15];
#pragma unroll
        for (int ot = 0; ot < 2; ++ot)
#pragma unroll
            for (int bt = 0; bt < 2; ++bt) {
                float4 xx = bt ? x1 : x0;
                float o0 = xx.x * acc[0][ot][bt][0] + xx.y * acc[1][ot][bt][0] + xx.z * acc[2][ot][bt][0] + xx.w * acc[3][ot][bt][0];
                float o1 = xx.x * acc[0][ot][bt][1] + xx.y * acc[1][ot][bt][1] + xx.z * acc[2][ot][bt][1] + xx.w * acc[3][ot][bt][1];
                float o2 = xx.x * acc[0][ot][bt][2] + xx.y * acc[1][ot][bt][2] + xx.z * acc[2][ot][bt][2] + xx.w * acc[3][ot][bt][2];
                float o3 = xx.x * acc[0][ot][bt][3] + xx.y * acc[1][ot][bt][3] + xx.z * acc[2][ot][bt][3] + xx.w * acc[3][ot][bt][3];
                uint2 dv; dv.x = pk16(o0, o1); dv.y = pk16(o2, o3);
                // o-group base = 32w + 16ot + 4q  -> chunk = 4w + 2ot + (q>>1), half = q&1
                int chunk = (4 * w + 2 * ot + (q >> 1)) ^ r15;
                *(uint2*)(wbp + (bt * 16 + r15) * 256 + (chunk << 4) + (q & 1) * 8) = dv;
            }
        __syncthreads();
    }

    // Final contraction: logits[b,c] = sum_i state[b,i] * sum_m w_last[c,i,m].
    if (tid < 128) {
        float s = 0.f;
#pragma unroll
        for (int m = 0; m < 4; ++m) s += w_last[(c * 128 + tid) * 4 + m];
        uf[tid] = s;
    }
    __syncthreads();
    {
        int b = tid & 31, seg = tid >> 5;
        float p = 0.f;
#pragma unroll
        for (int k2 = 0; k2 < 16; ++k2) {
            int i = seg * 16 + k2;           // final state in buffer 0
            ushort_t hv = *(const ushort_t*)(st + b * 256 + (((i >> 3) ^ (b & 15)) << 4) + (i & 7) * 2);
            union { ushort_t u; _Float16 hh; } cv; cv.u = hv;
            p += (float)cv.hh * uf[i];
        }
        red[seg * 32 + b] = p;
    }
    __syncthreads();
    if (tid < 32) {
        float s = 0.f;
#pragma unroll
        for (int sg = 0; sg < 8; ++sg) s += red[sg * 32 + tid];
        logits[(b0 + tid) * C_ + c] = s;
    }
}

// Log-softmax over C=10, output FLOAT32.
__global__ void k_lsm(const float* __restrict__ logits, float* __restrict__ out) {
    int b = blockIdx.x * 256 + threadIdx.x;
    float x[C_];
    float mx = -1e30f;
#pragma unroll
    for (int c = 0; c < C_; ++c) { x[c] = logits[b * C_ + c]; mx = fmaxf(mx, x[c]); }
    float s = 0.f;
#pragma unroll
    for (int c = 0; c < C_; ++c) s += __expf(x[c] - mx);
    float lse = mx + __logf(s);
#pragma unroll
    for (int c = 0; c < C_; ++c) out[b * C_ + c] = x[c] - lse;
}

extern "C" void kernel_launch(void* const* d_in, const int* in_sizes, int n_in,
                              void* d_out, int out_size, void* d_ws, size_t ws_size,
                              hipStream_t stream) {
    const float* tensor  = (const float*)d_in[0];   // (B,N)      f32
    const float* w_first = (const float*)d_in[1];   // (C,1,M,R)  f32
    const float* w_mid   = (const float*)d_in[2];   // (C,R,M,R)  f32
    const float* w_last  = (const float*)d_in[3];   // (C,R,M,1)  f32
    char* ws = (char*)d_ws;
    uint2* div16 = (uint2*)ws;                               // 1 MiB
    uint4* wt    = (uint4*)(ws + 1048576);                   // 1.31 MB
    float* logits = (float*)(ws + 1048576 + 1310720);        // 80 KB
    float* out = (float*)d_out;                              // (B,C) f32

    k_pre<<<832, 256, 0, stream>>>(tensor, w_mid, div16, wt);
    k_main<<<dim3(64, 10), 256, 0, stream>>>(div16, wt, w_first, w_last, logits);
    k_lsm<<<8, 256, 0, stream>>>(logits, out);
}